// Round 9
// baseline (130.770 us; speedup 1.0000x reference)
//
#include <hip/hip_runtime.h>

// Fused tensor-field + 3-layer MLP for MI355X (gfx950). Round 9.
//
// R8 post-mortem: kernel ~38-42us (now faster than the harness's 44us poison
// memsets, fell out of top-5). Issue-bound floor is ~10us; the 4x gap is
// latency stalls: serial gather->barrier->compute with a 2-level dependent
// load chain (idx -> corners) fully exposed per block.
//
// This round: 2 tiles/block (grid 2048), double-buffered f_T. Tile t+1's idx
// loads issue before tile t's compute; corner loads issue mid-compute (idx
// waitcnt covered by ~700cyc of MFMA); combine+ds_write after compute; one
// barrier per tile. Per-block staging (wt/zf/frags) amortized 2x. Costs ~48
// staged VGPR -> expect ~150 VGPR, 3 blocks/CU.
// Compute core unchanged from R7 (verified): sigma-striped L1 so h stays in
// registers, zero cross-lane L1->L2, in-register L3 dot + 2 shfl_xor.

typedef float f32x4 __attribute__((ext_vector_type(4)));
typedef short bf16x8 __attribute__((ext_vector_type(8)));

constexpr int NPIX = 512 * 512;
constexpr int PPT  = 64;    // pixels per tile
constexpr int TPB  = 2;     // tiles per block

union FragU { unsigned int u[4]; uint4 v; bf16x8 s; };

// D[15:0] = top16 of e0 (bf16 truncate), D[31:16] = top16 of e1
__device__ __forceinline__ unsigned int pack_top16(float e0, float e1) {
    return __builtin_amdgcn_perm(__float_as_uint(e1), __float_as_uint(e0), 0x07060302u);
}
__device__ __forceinline__ float trunc_bf16(float x) {
    return __uint_as_float(__float_as_uint(x) & 0xFFFF0000u);
}

__global__ __launch_bounds__(256) void field_mlp_mfma4(
    const float* __restrict__ z,        // [8]
    const float* __restrict__ data,     // [512,512,32]
    const float* __restrict__ z_data,   // [64,32]
    const float* __restrict__ lerp_w,   // [NPIX,2]
    const int* __restrict__ x0a, const int* __restrict__ y0a,
    const int* __restrict__ x1a, const int* __restrict__ y1a,
    const float* __restrict__ W1, const float* __restrict__ b1,
    const float* __restrict__ W2, const float* __restrict__ b2,
    const float* __restrict__ W3, const float* __restrict__ b3,
    float* __restrict__ out)            // [8,1,512,512]
{
    __shared__ float f_T[2][PPT][36];                    // double-buffered [px][feat]
    __shared__ float zf_lds[8][36];
    __shared__ float bias_lds[2][36];
    __shared__ float w3_lds[36];
    __shared__ __align__(16) unsigned int wt_lds[4][32][20]; // W1h,W1l,W2h,W2l [n][k-pairs]

    const int tid = threadIdx.x;

    // ---- one-time staging: z-feature, biases, weight transpose+split ----
    {
        const int b = tid >> 5, i = tid & 31;
        const float zn = 63.0f * z[b];               // Z_MIN=0, Z_MAX=1
        int z0 = (int)zn; z0 = max(0, min(z0, 63));
        const int z1i = min(z0 + 1, 63);
        const float zl = zn - truncf(zn);
        zf_lds[b][i] = z_data[z0 * 32 + i] * (1.0f - zl) + z_data[z1i * 32 + i] * zl;
    }
    if (tid < 32) {
        bias_lds[0][tid] = b1[tid];
        bias_lds[1][tid] = b2[tid];
        w3_lds[tid]      = W3[tid];
    }
    {
        const int n = tid & 31, kc = (tid >> 5) * 4, kw = (tid >> 5) * 2;
#pragma unroll
        for (int m = 0; m < 2; ++m) {
            const float* Wm = m ? W2 : W1;
            const float x0 = Wm[(kc + 0) * 32 + n];
            const float x1 = Wm[(kc + 1) * 32 + n];
            const float x2 = Wm[(kc + 2) * 32 + n];
            const float x3 = Wm[(kc + 3) * 32 + n];
            wt_lds[2 * m][n][kw]     = pack_top16(x0, x1);
            wt_lds[2 * m][n][kw + 1] = pack_top16(x2, x3);
            wt_lds[2 * m + 1][n][kw]     = pack_top16(x0 - trunc_bf16(x0), x1 - trunc_bf16(x1));
            wt_lds[2 * m + 1][n][kw + 1] = pack_top16(x2 - trunc_bf16(x2), x3 - trunc_bf16(x3));
        }
    }

    // ---- pipelined gather state (registers) ----
    int   coff[2][4];      // corner cell offsets (units of f32x4)
    float cw[2][4];        // bilinear weights
    f32x4 creg[2][4];      // staged corner data

    auto tile_idx = [&](int tile) {
        const int pbase = blockIdx.x * (TPB * PPT) + tile * PPT;
#pragma unroll
        for (int u = 0; u < 2; ++u) {
            const int unit = tid + u * 256;
            const int pxl = unit >> 3, ch = unit & 7;
            const int p = pbase + pxl;
            const int ix0 = x0a[p], iy0 = y0a[p], ix1 = x1a[p], iy1 = y1a[p];
            const float2 w2 = *(const float2*)(lerp_w + 2 * p);
            const float wx = w2.x, wy = w2.y;
            cw[u][0] = (1.0f - wx) * (1.0f - wy);
            cw[u][1] = wx * (1.0f - wy);
            cw[u][2] = (1.0f - wx) * wy;
            cw[u][3] = wx * wy;
            coff[u][0] = (iy0 * 512 + ix0) * 8 + ch;
            coff[u][1] = (iy0 * 512 + ix1) * 8 + ch;
            coff[u][2] = (iy1 * 512 + ix0) * 8 + ch;
            coff[u][3] = (iy1 * 512 + ix1) * 8 + ch;
        }
    };
    auto tile_corners = [&]() {
        const f32x4* base = (const f32x4*)data;
#pragma unroll
        for (int u = 0; u < 2; ++u)
#pragma unroll
            for (int c = 0; c < 4; ++c) creg[u][c] = base[coff[u][c]];
    };
    auto tile_write = [&](int buf) {
#pragma unroll
        for (int u = 0; u < 2; ++u) {
            const int unit = tid + u * 256;
            const int pxl = unit >> 3, ch = unit & 7;
            const f32x4 v = creg[u][0] * cw[u][0] + creg[u][1] * cw[u][1]
                          + creg[u][2] * cw[u][2] + creg[u][3] * cw[u][3];
            *(f32x4*)&f_T[buf][pxl][ch * 4] = v;
        }
    };

    // ---- prologue: gather tile 0 (idx latency exposed once per block) ----
    tile_idx(0);
    tile_corners();
    __syncthreads();                 // zf/bias/wt visible

    // ---- preload per-wave fragments (LDS reads overlap corner loads) ----
    const int l  = tid & 63, w = tid >> 6;   // wave handles batches 2w, 2w+1
    const int lg = l >> 4,  lr = l & 15;
    const int srow = ((lr >> 2) << 3) + (lr & 3);   // sigma-stripe row

    FragU W1f[2][2], W2f[2][2];
#pragma unroll
    for (int t = 0; t < 2; ++t) {
        W1f[t][0].v = *(const uint4*)&wt_lds[0][srow + 4 * t][lg * 4];
        W1f[t][1].v = *(const uint4*)&wt_lds[1][srow + 4 * t][lg * 4];
        W2f[t][0].v = *(const uint4*)&wt_lds[2][t * 16 + lr][lg * 4];
        W2f[t][1].v = *(const uint4*)&wt_lds[3][t * 16 + lr][lg * 4];
    }
    f32x4 zva[2], zvb[2], b1v[2], b2v[2], w3v[2];
#pragma unroll
    for (int bb = 0; bb < 2; ++bb) {
        zva[bb] = *(const f32x4*)&zf_lds[2 * w + bb][lg * 8];
        zvb[bb] = *(const f32x4*)&zf_lds[2 * w + bb][lg * 8 + 4];
    }
#pragma unroll
    for (int t = 0; t < 2; ++t) {
        b1v[t] = *(const f32x4*)&bias_lds[0][8 * lg + 4 * t];
        b2v[t] = *(const f32x4*)&bias_lds[1][t * 16 + 4 * lg];
        w3v[t] = *(const f32x4*)&w3_lds[t * 16 + 4 * lg];
    }
    const float b3s = b3[0];
    const f32x4 vzero = {0.0f, 0.0f, 0.0f, 0.0f};

    tile_write(0);                   // waitcnt on tile-0 corners lands here
    __syncthreads();                 // f_T[0] visible

    // ---- one px-group (16 pixels x 2 batches) of MFMA compute ----
    auto compute_quarter = [&](int buf, int pxg, int obase) {
        const int px = pxg * 16 + lr;
        const f32x4 ff0 = *(const f32x4*)&f_T[buf][px][lg * 8];
        const f32x4 ff1 = *(const f32x4*)&f_T[buf][px][lg * 8 + 4];
#pragma unroll
        for (int bb = 0; bb < 2; ++bb) {
            const f32x4 ea = ff0 * zva[bb];
            const f32x4 eb = ff1 * zvb[bb];
            FragU Eh;
            Eh.u[0] = pack_top16(ea[0], ea[1]);
            Eh.u[1] = pack_top16(ea[2], ea[3]);
            Eh.u[2] = pack_top16(eb[0], eb[1]);
            Eh.u[3] = pack_top16(eb[2], eb[3]);
            f32x4 hv[2];
#pragma unroll
            for (int t = 0; t < 2; ++t) {
                f32x4 a = __builtin_amdgcn_mfma_f32_16x16x32_bf16(W1f[t][1].s, Eh.s, vzero, 0, 0, 0);
                a = __builtin_amdgcn_mfma_f32_16x16x32_bf16(W1f[t][0].s, Eh.s, a, 0, 0, 0);
                a = a + b1v[t];
#pragma unroll
                for (int r = 0; r < 4; ++r) a[r] = fmaxf(a[r], 0.0f);
                hv[t] = a;
            }
            FragU Hh, Hl;
            Hh.u[0] = pack_top16(hv[0][0], hv[0][1]);
            Hh.u[1] = pack_top16(hv[0][2], hv[0][3]);
            Hh.u[2] = pack_top16(hv[1][0], hv[1][1]);
            Hh.u[3] = pack_top16(hv[1][2], hv[1][3]);
            f32x4 hl0 = hv[0], hl1 = hv[1];
#pragma unroll
            for (int r = 0; r < 4; ++r) {
                hl0[r] -= trunc_bf16(hv[0][r]);
                hl1[r] -= trunc_bf16(hv[1][r]);
            }
            Hl.u[0] = pack_top16(hl0[0], hl0[1]);
            Hl.u[1] = pack_top16(hl0[2], hl0[3]);
            Hl.u[2] = pack_top16(hl1[0], hl1[1]);
            Hl.u[3] = pack_top16(hl1[2], hl1[3]);
            float o = 0.0f;
#pragma unroll
            for (int t = 0; t < 2; ++t) {
                f32x4 a = __builtin_amdgcn_mfma_f32_16x16x32_bf16(W2f[t][0].s, Hl.s, vzero, 0, 0, 0);
                a = __builtin_amdgcn_mfma_f32_16x16x32_bf16(W2f[t][1].s, Hh.s, a, 0, 0, 0);
                a = __builtin_amdgcn_mfma_f32_16x16x32_bf16(W2f[t][0].s, Hh.s, a, 0, 0, 0);
                a = a + b2v[t];
#pragma unroll
                for (int r = 0; r < 4; ++r)
                    o = fmaf(fmaxf(a[r], 0.0f), w3v[t][r], o);
            }
            o += __shfl_xor(o, 16);
            o += __shfl_xor(o, 32);
            o += b3s;
            if (l < 16)
                __builtin_nontemporal_store(o, out + (2 * w + bb) * NPIX + obase + px);
        }
    };

    // ---- tile loop: prefetch t+1 under compute of t ----
#pragma unroll
    for (int t = 0; t < TPB; ++t) {
        const int obase = blockIdx.x * (TPB * PPT) + t * PPT;
        if (t + 1 < TPB) tile_idx(t + 1);       // issue idx loads
        compute_quarter(t & 1, 0, obase);
        compute_quarter(t & 1, 1, obase);
        if (t + 1 < TPB) tile_corners();        // idx waitcnt covered; issue corners
        compute_quarter(t & 1, 2, obase);
        compute_quarter(t & 1, 3, obase);
        if (t + 1 < TPB) {
            tile_write((t + 1) & 1);            // corner waitcnt lands here
            __syncthreads();                    // f_T[(t+1)&1] visible
        }
    }
}

extern "C" void kernel_launch(void* const* d_in, const int* in_sizes, int n_in,
                              void* d_out, int out_size, void* d_ws, size_t ws_size,
                              hipStream_t stream) {
    const float* zp      = (const float*)d_in[0];
    const float* data    = (const float*)d_in[1];
    const float* z_data  = (const float*)d_in[2];
    const float* lerp_w  = (const float*)d_in[3];
    const int*   x0      = (const int*)d_in[4];
    const int*   y0      = (const int*)d_in[5];
    const int*   x1      = (const int*)d_in[6];
    const int*   y1      = (const int*)d_in[7];
    const float* W1      = (const float*)d_in[8];
    const float* b1      = (const float*)d_in[9];
    const float* W2      = (const float*)d_in[10];
    const float* b2      = (const float*)d_in[11];
    const float* W3      = (const float*)d_in[12];
    const float* b3      = (const float*)d_in[13];
    float* out = (float*)d_out;

    dim3 grid(NPIX / (TPB * PPT));   // 2048 blocks x 2 tiles
    dim3 block(256);
    hipLaunchKernelGGL(field_mlp_mfma4, grid, block, 0, stream,
                       zp, data, z_data, lerp_w, x0, y0, x1, y1,
                       W1, b1, W2, b2, W3, b3, out);
}

// Round 10
// 129.581 us; speedup vs baseline: 1.0092x; 1.0092x over previous
//
#include <hip/hip_runtime.h>

// Fused tensor-field + 3-layer MLP for MI355X (gfx950). Round 10.
//
// R9 post-mortem: explicit 2-tile prefetch FALSIFIED (dur unchanged); its +72
// VGPR of staged state tripped the allocator's occupancy heuristic: VGPR=80
// vs ~150 live -> scratch spills (WRITE 11.1MB vs 8.39 stored, FETCH 36 vs
// 20MB, VALU-busy 22.6us vs ~5us hand count = 4x mov/addressing bloat).
// TLP (7 blocks/CU) was already hiding the gather latency in R8.
//
// This round, ONE variable vs R8: __launch_bounds__(256, 1). min-waves/EU=1
// removes the allocator's occupancy floor -> ~110 live regs allocated
// spill-free (expect VGPR 100-144, still 3-4 waves/SIMD + 16 waves/SIMD of
// block-level TLP). Falsifiable: WRITE_SIZE returns to 8192 KB exactly.
//
// Compute core (verified R7/R8): transposed MFMA formulation, sigma-striped
// L1 (sigma(p)=8*(p>>2)+(p&3)) so each lane's L1 accumulators are exactly its
// L2 B-frag k-run -> h never leaves registers; zero cross-lane L1->L2;
// L3 = in-register dot + 2 shfl_xor. 2-term split L1, 3-term L2.

typedef float f32x4 __attribute__((ext_vector_type(4)));
typedef short bf16x8 __attribute__((ext_vector_type(8)));

constexpr int NPIX = 512 * 512;
constexpr int PPB  = 64;    // pixels per block; rows = 8 batches x 64 px = 512

union FragU { unsigned int u[4]; uint4 v; bf16x8 s; };

// D[15:0] = top16 of e0 (bf16 truncate), D[31:16] = top16 of e1
__device__ __forceinline__ unsigned int pack_top16(float e0, float e1) {
    return __builtin_amdgcn_perm(__float_as_uint(e1), __float_as_uint(e0), 0x07060302u);
}
__device__ __forceinline__ float trunc_bf16(float x) {
    return __uint_as_float(__float_as_uint(x) & 0xFFFF0000u);
}

__global__ __launch_bounds__(256, 1) void field_mlp_mfma5(
    const float* __restrict__ z,        // [8]
    const float* __restrict__ data,     // [512,512,32]
    const float* __restrict__ z_data,   // [64,32]
    const float* __restrict__ lerp_w,   // [NPIX,2]
    const int* __restrict__ x0a, const int* __restrict__ y0a,
    const int* __restrict__ x1a, const int* __restrict__ y1a,
    const float* __restrict__ W1, const float* __restrict__ b1,
    const float* __restrict__ W2, const float* __restrict__ b2,
    const float* __restrict__ W3, const float* __restrict__ b3,
    float* __restrict__ out)            // [8,1,512,512]
{
    __shared__ float f_T[PPB][36];                       // [px][feat], pad 36
    __shared__ float zf_lds[8][36];                      // [batch][feat]
    __shared__ float bias_lds[2][36];                    // b1, b2
    __shared__ float w3_lds[36];
    __shared__ __align__(16) unsigned int wt_lds[4][32][20]; // W1h,W1l,W2h,W2l [n][k-pairs]

    const int tid = threadIdx.x;

    // ---- z-feature: 8 batches x 32 feats ----
    {
        const int b = tid >> 5, i = tid & 31;
        const float zn = 63.0f * z[b];               // Z_MIN=0, Z_MAX=1
        int z0 = (int)zn; z0 = max(0, min(z0, 63));
        const int z1i = min(z0 + 1, 63);
        const float zl = zn - truncf(zn);
        zf_lds[b][i] = z_data[z0 * 32 + i] * (1.0f - zl) + z_data[z1i * 32 + i] * zl;
    }
    // ---- biases / w3 ----
    if (tid < 32) {
        bias_lds[0][tid] = b1[tid];
        bias_lds[1][tid] = b2[tid];
        w3_lds[tid]      = W3[tid];
    }
    // ---- cooperative bilinear gather: 2 units/thread, unit = (px, 4-feat chunk) ----
#pragma unroll
    for (int u = 0; u < 2; ++u) {
        const int unit = tid + u * 256;
        const int pxl = unit >> 3, ch = unit & 7;
        const int p = blockIdx.x * PPB + pxl;
        const int ix0 = x0a[p], iy0 = y0a[p], ix1 = x1a[p], iy1 = y1a[p];
        const float2 w2 = *(const float2*)(lerp_w + 2 * p);
        const float wx = w2.x, wy = w2.y;
        const float w00 = (1.0f - wx) * (1.0f - wy);
        const float w01 = wx * (1.0f - wy);
        const float w10 = (1.0f - wx) * wy;
        const float w11 = wx * wy;
        const f32x4* base = (const f32x4*)data;
        const f32x4 c00 = base[(iy0 * 512 + ix0) * 8 + ch];
        const f32x4 c01 = base[(iy0 * 512 + ix1) * 8 + ch];
        const f32x4 c10 = base[(iy1 * 512 + ix0) * 8 + ch];
        const f32x4 c11 = base[(iy1 * 512 + ix1) * 8 + ch];
        const f32x4 v = c00 * w00 + c01 * w01 + c10 * w10 + c11 * w11;
        *(f32x4*)&f_T[pxl][ch * 4] = v;              // b128 write
    }
    // ---- W1/W2 transpose + hi/lo split: thread = (n, 4-k chunk) ----
    {
        const int n = tid & 31, kc = (tid >> 5) * 4, kw = (tid >> 5) * 2;
#pragma unroll
        for (int m = 0; m < 2; ++m) {
            const float* Wm = m ? W2 : W1;
            const float x0 = Wm[(kc + 0) * 32 + n];
            const float x1 = Wm[(kc + 1) * 32 + n];
            const float x2 = Wm[(kc + 2) * 32 + n];
            const float x3 = Wm[(kc + 3) * 32 + n];
            wt_lds[2 * m][n][kw]     = pack_top16(x0, x1);
            wt_lds[2 * m][n][kw + 1] = pack_top16(x2, x3);
            wt_lds[2 * m + 1][n][kw]     = pack_top16(x0 - trunc_bf16(x0), x1 - trunc_bf16(x1));
            wt_lds[2 * m + 1][n][kw + 1] = pack_top16(x2 - trunc_bf16(x2), x3 - trunc_bf16(x3));
        }
    }
    __syncthreads();

    const int l  = tid & 63, w = tid >> 6;           // wave handles batches 2w, 2w+1
    const int lg = l >> 4,  lr = l & 15;
    const int srow = ((lr >> 2) << 3) + (lr & 3);    // sigma-stripe row for W1 tiles

    // ---- preload fragments (reused across all m-tiles) ----
    FragU W1f[2][2], W2f[2][2];                      // [tile][hi=0/lo=1]
#pragma unroll
    for (int t = 0; t < 2; ++t) {
        W1f[t][0].v = *(const uint4*)&wt_lds[0][srow + 4 * t][lg * 4];
        W1f[t][1].v = *(const uint4*)&wt_lds[1][srow + 4 * t][lg * 4];
        W2f[t][0].v = *(const uint4*)&wt_lds[2][t * 16 + lr][lg * 4];
        W2f[t][1].v = *(const uint4*)&wt_lds[3][t * 16 + lr][lg * 4];
    }
    f32x4 zva[2], zvb[2], b1v[2], b2v[2], w3v[2];
#pragma unroll
    for (int bb = 0; bb < 2; ++bb) {
        zva[bb] = *(const f32x4*)&zf_lds[2 * w + bb][lg * 8];
        zvb[bb] = *(const f32x4*)&zf_lds[2 * w + bb][lg * 8 + 4];
    }
#pragma unroll
    for (int t = 0; t < 2; ++t) {
        b1v[t] = *(const f32x4*)&bias_lds[0][8 * lg + 4 * t];   // sigma-striped n
        b2v[t] = *(const f32x4*)&bias_lds[1][t * 16 + 4 * lg];
        w3v[t] = *(const f32x4*)&w3_lds[t * 16 + 4 * lg];
    }
    const float b3s = b3[0];
    const f32x4 vzero = {0.0f, 0.0f, 0.0f, 0.0f};
    float* const outp = out + blockIdx.x * PPB;

#pragma unroll
    for (int pxg = 0; pxg < 4; ++pxg) {
        const int px = pxg * 16 + lr;                // this lane's pixel (as B-col)
        const f32x4 ff0 = *(const f32x4*)&f_T[px][lg * 8];
        const f32x4 ff1 = *(const f32x4*)&f_T[px][lg * 8 + 4];
#pragma unroll
        for (int bb = 0; bb < 2; ++bb) {
            // e^T B-frag: e = f .* zf (f32), truncate-pack hi only (2-term L1)
            const f32x4 ea = ff0 * zva[bb];
            const f32x4 eb = ff1 * zvb[bb];
            FragU Eh;
            Eh.u[0] = pack_top16(ea[0], ea[1]);
            Eh.u[1] = pack_top16(ea[2], ea[3]);
            Eh.u[2] = pack_top16(eb[0], eb[1]);
            Eh.u[3] = pack_top16(eb[2], eb[3]);
            // L1: h^T tiles (sigma-striped): acc[t] reg r holds n = 8lg + r + 4t
            f32x4 hv[2];
#pragma unroll
            for (int t = 0; t < 2; ++t) {
                f32x4 a = __builtin_amdgcn_mfma_f32_16x16x32_bf16(W1f[t][1].s, Eh.s, vzero, 0, 0, 0);
                a = __builtin_amdgcn_mfma_f32_16x16x32_bf16(W1f[t][0].s, Eh.s, a, 0, 0, 0);
                a = a + b1v[t];
#pragma unroll
                for (int r = 0; r < 4; ++r) a[r] = fmaxf(a[r], 0.0f);
                hv[t] = a;
            }
            // lane now holds h[8lg .. 8lg+7] = L2 B-frag k-run. Split hi/lo.
            FragU Hh, Hl;
            Hh.u[0] = pack_top16(hv[0][0], hv[0][1]);
            Hh.u[1] = pack_top16(hv[0][2], hv[0][3]);
            Hh.u[2] = pack_top16(hv[1][0], hv[1][1]);
            Hh.u[3] = pack_top16(hv[1][2], hv[1][3]);
            f32x4 hl0 = hv[0], hl1 = hv[1];
#pragma unroll
            for (int r = 0; r < 4; ++r) {
                hl0[r] -= trunc_bf16(hv[0][r]);
                hl1[r] -= trunc_bf16(hv[1][r]);
            }
            Hl.u[0] = pack_top16(hl0[0], hl0[1]);
            Hl.u[1] = pack_top16(hl0[2], hl0[3]);
            Hl.u[2] = pack_top16(hl1[0], hl1[1]);
            Hl.u[3] = pack_top16(hl1[2], hl1[3]);
            // L2: 3-term, contiguous n-tiles
            float o = 0.0f;
#pragma unroll
            for (int t = 0; t < 2; ++t) {
                f32x4 a = __builtin_amdgcn_mfma_f32_16x16x32_bf16(W2f[t][0].s, Hl.s, vzero, 0, 0, 0);
                a = __builtin_amdgcn_mfma_f32_16x16x32_bf16(W2f[t][1].s, Hh.s, a, 0, 0, 0);
                a = __builtin_amdgcn_mfma_f32_16x16x32_bf16(W2f[t][0].s, Hh.s, a, 0, 0, 0);
                a = a + b2v[t];
#pragma unroll
                for (int r = 0; r < 4; ++r)
                    o = fmaf(fmaxf(a[r], 0.0f), w3v[t][r], o);
            }
            // L3 reduce across lg groups (lanes lr, lr+16, lr+32, lr+48)
            o += __shfl_xor(o, 16);
            o += __shfl_xor(o, 32);
            o += b3s;
            if (l < 16)
                __builtin_nontemporal_store(o, outp + (2 * w + bb) * NPIX + px);
        }
    }
}

extern "C" void kernel_launch(void* const* d_in, const int* in_sizes, int n_in,
                              void* d_out, int out_size, void* d_ws, size_t ws_size,
                              hipStream_t stream) {
    const float* zp      = (const float*)d_in[0];
    const float* data    = (const float*)d_in[1];
    const float* z_data  = (const float*)d_in[2];
    const float* lerp_w  = (const float*)d_in[3];
    const int*   x0      = (const int*)d_in[4];
    const int*   y0      = (const int*)d_in[5];
    const int*   x1      = (const int*)d_in[6];
    const int*   y1      = (const int*)d_in[7];
    const float* W1      = (const float*)d_in[8];
    const float* b1      = (const float*)d_in[9];
    const float* W2      = (const float*)d_in[10];
    const float* b2      = (const float*)d_in[11];
    const float* W3      = (const float*)d_in[12];
    const float* b3      = (const float*)d_in[13];
    float* out = (float*)d_out;

    dim3 grid(NPIX / PPB);   // 4096 blocks
    dim3 block(256);
    hipLaunchKernelGGL(field_mlp_mfma5, grid, block, 0, stream,
                       zp, data, z_data, lerp_w, x0, y0, x1, y1,
                       W1, b1, W2, b2, W3, b3, out);
}